// Round 9
// baseline (161.830 us; speedup 1.0000x reference)
//
#include <hip/hip_runtime.h>
#include <hip/hip_bf16.h>
#include <stdint.h>

typedef __bf16 bf16;
typedef __bf16 bf16x8 __attribute__((ext_vector_type(8)));
typedef __bf16 bf16x4 __attribute__((ext_vector_type(4)));
typedef float  f32x4  __attribute__((ext_vector_type(4)));
typedef unsigned int u32;

typedef __attribute__((address_space(1))) u32 gu32;
typedef __attribute__((address_space(3))) u32 lu32;

__device__ __forceinline__ void gld_lds16(const void* g, void* l) {
  __builtin_amdgcn_global_load_lds((gu32*)(uintptr_t)g, (lu32*)(u32)(uintptr_t)l, 16, 0, 0);
}

__device__ __forceinline__ f32x4 mfma_bf16_16x16x32(bf16x8 a, bf16x8 b, f32x4 c) {
  return __builtin_amdgcn_mfma_f32_16x16x32_bf16(a, b, c, 0, 0, 0);
}

#define LGKM0 do { asm volatile("s_waitcnt lgkmcnt(0)" ::: "memory"); \
                   __builtin_amdgcn_sched_barrier(0); } while (0)
#define VMC(n) do { asm volatile("s_waitcnt vmcnt(" #n ")" ::: "memory"); } while (0)
#define BAR __builtin_amdgcn_s_barrier()
#define PRIO1 __builtin_amdgcn_s_setprio(1)
#define PRIO0 __builtin_amdgcn_s_setprio(0)

// ---------------- cast x (fp32 -> bf16), 8 elems/thread ----------------
__global__ __launch_bounds__(256) void k_cast_x(const float* __restrict__ x,
                                                bf16* __restrict__ xb) {
  size_t i = (size_t)blockIdx.x * 256 + threadIdx.x;
  const float4* p = (const float4*)x + i * 2;
  float4 a = p[0], b = p[1];
  bf16x8 o;
  o[0] = (bf16)a.x; o[1] = (bf16)a.y; o[2] = (bf16)a.z; o[3] = (bf16)a.w;
  o[4] = (bf16)b.x; o[5] = (bf16)b.y; o[6] = (bf16)b.z; o[7] = (bf16)b.w;
  *(bf16x8*)(xb + i * 8) = o;
}

// -------- transpose + PERMUTE w [512][1536] f32 -> wT [1536][512] bf16 --------
// kv tile hp (wT rows 512+hp*256..+255) = [k_{2hp} | k_{2hp+1} | v_{2hp} | v_{2hp+1}].
__global__ __launch_bounds__(256) void k_prep_w(const float* __restrict__ w,
                                                bf16* __restrict__ wT) {
  int idx = blockIdx.x * 256 + threadIdx.x;
  int r = idx >> 9;
  int k = idx & 511;
  int c;
  if (r < 512) {
    c = r;
  } else {
    int rr = r - 512;
    int hp = rr >> 8;
    int q2 = (rr >> 6) & 3;
    int d = r & 63;
    int h = 2 * hp + (q2 & 1);
    c = ((q2 < 2) ? 512 : 1024) + h * 64 + d;
  }
  wT[idx] = (bf16)w[k * 1536 + c];
}

template <int MH, int NH>
__device__ __forceinline__ void mm(f32x4 (&acc)[8][4],
                                   const bf16x8 (&a)[4][2],
                                   const bf16x8 (&b)[2][2]) {
#pragma unroll
  for (int fm = 0; fm < 4; ++fm)
#pragma unroll
    for (int fn = 0; fn < 2; ++fn)
#pragma unroll
      for (int ks = 0; ks < 2; ++ks)
        acc[MH * 4 + fm][NH * 2 + fn] =
            mfma_bf16_16x16x32(a[fm][ks], b[fn][ks], acc[MH * 4 + fm][NH * 2 + fn]);
}

// ---------------- QKV GEMM: A via LDS (64KB dbuf), B DIRECT L2->register ----------
// wT is 1.5MB -> L2-resident. B frags loaded global->reg one step ahead (no LDS,
// no barrier coupling, compiler-managed waits). LDS carries only A: 2x32KB dbuf.
// 2 phases/step, 32 MFMA each. Epilogue: q-LN store; kv: 2-round in-LDS dots (64KB).
__global__ __launch_bounds__(512, 2) void k_qkv_gemm(
    const bf16* __restrict__ A, const bf16* __restrict__ Bt,
    const float* __restrict__ qg, const float* __restrict__ qbeta,
    const float* __restrict__ kg, const float* __restrict__ kbeta,
    bf16* __restrict__ qh, float* __restrict__ dTp)
{
  extern __shared__ bf16 lds[];   // 65536 B: A buf0 @0, A buf1 @32768
  const int tid = threadIdx.x;
  const int lane = tid & 63;
  const int w = tid >> 6;        // 0..7
  const int wm = w >> 2;         // 0..1
  const int wn = w & 3;          // 0..3

  const int wg = blockIdx.x;
  const int swz = (wg & 7) * 96 + (wg >> 3);
  const int tn = swz % 6;
  const int tm = swz / 6;

  // A staging: buf at byte buf*32768; slot s (rows (vr>>6)*128 + s*64 + (vr&63)).
  auto stA = [&](int buf, int slot, int ktile) {
#pragma unroll
    for (int i = 0; i < 2; ++i) {
      int vr = i * 64 + w * 8 + (lane >> 3);
      int grow = tm * 256 + (vr >> 6) * 128 + slot * 64 + (vr & 63);
      int gk = ktile * 64 + (((lane & 7) ^ (vr & 7)) * 8);
      gld_lds16(A + (size_t)grow * 512 + gk,
                (char*)lds + buf * 32768 + slot * 16384 + i * 8192 + w * 1024);
    }
  };
  auto rdA = [&](int buf, int mh, bf16x8 (&fr)[4][2]) {
    const bf16* base = lds + buf * 16384 + mh * 8192;
#pragma unroll
    for (int f = 0; f < 4; ++f) {
      int vr = wm * 64 + f * 16 + (lane & 15);
#pragma unroll
      for (int ks = 0; ks < 2; ++ks) {
        int pb = (ks * 4 + (lane >> 4)) ^ (vr & 7);
        fr[f][ks] = *(const bf16x8*)(base + vr * 64 + pb * 8);
      }
    }
  };
  // B fragment direct load: col = tn*256 + wn*64 + nh*32 + f*16 + (lane&15),
  // k = t*64 + ks*32 + (lane>>4)*8.  (16-lane groups consume full 64B lines.)
  const bf16* bbase = Bt + ((size_t)(tn * 256 + wn * 64) + (lane & 15)) * 512
                         + (lane >> 4) * 8;
  auto loadB = [&](bf16x8 (&bb)[2][2][2], int t) {
#pragma unroll
    for (int nh = 0; nh < 2; ++nh)
#pragma unroll
      for (int f = 0; f < 2; ++f)
#pragma unroll
        for (int ks = 0; ks < 2; ++ks)
          bb[nh][f][ks] = *(const bf16x8*)(bbase + (size_t)(nh * 32 + f * 16) * 512
                                                 + t * 64 + ks * 32);
  };

  bf16x8 afr[4][2];
  bf16x8 bc[2][2][2], bn[2][2][2];
  f32x4 acc[8][4];
  {
    f32x4 z = {0.f, 0.f, 0.f, 0.f};
#pragma unroll
    for (int m = 0; m < 8; ++m)
#pragma unroll
      for (int n = 0; n < 4; ++n) acc[m][n] = z;
  }

  // ---- prologue: stage A(0); load B(0) ----
  stA(0, 0, 0); stA(0, 1, 0);
  loadB(bc, 0);
  VMC(8);                     // 4 A-glds done (8 B-loads may fly; compiler waits uses)
  BAR;

#pragma unroll
  for (int t = 0; t < 8; ++t) {
    const int d = t & 1;
    // ---- half 1: read A0 frags; stage A(t+1) slot0; MFMA quadrants <0,*>
    rdA(d, 0, afr);
    if (t < 7) stA(d ^ 1, 0, t + 1);
    BAR;
    LGKM0;
    PRIO1; mm<0, 0>(acc, afr, bc[0]); mm<0, 1>(acc, afr, bc[1]); PRIO0;
    BAR;
    // ---- half 2: read A1 frags; stage A(t+1) slot1; prefetch B(t+1); MFMA <1,*>
    rdA(d, 1, afr);
    if (t < 7) { stA(d ^ 1, 1, t + 1); loadB(bn, t + 1); }
    BAR;
    LGKM0;
    PRIO1; mm<1, 0>(acc, afr, bc[0]); mm<1, 1>(acc, afr, bc[1]); PRIO0;
    if (t < 7) VMC(8);        // A(t+1)'s 4 glds landed; B(t+1) 8 loads may fly
    BAR;
    if (t < 7) {
#pragma unroll
      for (int nh = 0; nh < 2; ++nh)
#pragma unroll
        for (int f = 0; f < 2; ++f)
#pragma unroll
          for (int ks = 0; ks < 2; ++ks) bc[nh][f][ks] = bn[nh][f][ks];
    }
  }

  const int dlane = lane & 15;
  const int rsub = (lane >> 4) * 4;

  if (tn < 2) {
    // ---- q epilogue: LN + store [bh][n][d] ----
    const int hcol = tn * 4 + wn;
    float g4[4], b4[4];
#pragma unroll
    for (int fn = 0; fn < 4; ++fn) {
      g4[fn] = qg[fn * 16 + dlane];
      b4[fn] = qbeta[fn * 16 + dlane];
    }
#pragma unroll
    for (int m = 0; m < 8; ++m) {
      float mu[4], rs[4];
#pragma unroll
      for (int r = 0; r < 4; ++r) {
        float s  = acc[m][0][r] + acc[m][1][r] + acc[m][2][r] + acc[m][3][r];
        float s2 = acc[m][0][r] * acc[m][0][r] + acc[m][1][r] * acc[m][1][r]
                 + acc[m][2][r] * acc[m][2][r] + acc[m][3][r] * acc[m][3][r];
#pragma unroll
        for (int msk = 1; msk < 16; msk <<= 1) {
          s  += __shfl_xor(s, msk, 64);
          s2 += __shfl_xor(s2, msk, 64);
        }
        float mean = s * (1.0f / 64.0f);
        float var  = s2 * (1.0f / 64.0f) - mean * mean;
        mu[r] = mean;
        rs[r] = rsqrtf(var + 1e-5f);
      }
      int rowg = tm * 256 + wm * 128 + m * 16 + rsub;
      int bb2 = rowg >> 12, n0 = rowg & 4095;
      int bh = bb2 * 8 + hcol;
      bf16* dst = qh + ((size_t)bh * 4096 + n0) * 64;
#pragma unroll
      for (int r = 0; r < 4; ++r)
#pragma unroll
        for (int fn = 0; fn < 4; ++fn) {
          float xv = (acc[m][fn][r] - mu[r]) * rs[r] * g4[fn] + b4[fn];
          dst[(size_t)r * 64 + fn * 16 + dlane] = (bf16)xv;
        }
    }
  } else {
    // ---- kv epilogue: two rounds (one head each) in 64KB LDS ----
    // round r: waves with hloc==r write kT@0 / vT@32KB ([d][n] swizzled), then
    // ALL 8 waves compute the 64x64 dots partial for head 2hp+r.
    const int hp = tn - 2;
    const bool isK = (wn < 2);
    const int hloc = wn & 1;
    char* reg = (char*)lds + (isK ? 0 : 32768);
    float g4[4], b4[4];
    if (isK) {
#pragma unroll
      for (int fn = 0; fn < 4; ++fn) {
        g4[fn] = kg[fn * 16 + dlane];
        b4[fn] = kbeta[fn * 16 + dlane];
      }
    }
    const int qd = w & 3;        // e-row group
    const int jh = w >> 2;       // dk half
#pragma unroll
    for (int rnd = 0; rnd < 2; ++rnd) {
      if (hloc == rnd) {
#pragma unroll
        for (int m = 0; m < 8; ++m) {
          float mu[4] = {}, rs[4] = {};
          if (isK) {
#pragma unroll
            for (int r = 0; r < 4; ++r) {
              float s  = acc[m][0][r] + acc[m][1][r] + acc[m][2][r] + acc[m][3][r];
              float s2 = acc[m][0][r] * acc[m][0][r] + acc[m][1][r] * acc[m][1][r]
                       + acc[m][2][r] * acc[m][2][r] + acc[m][3][r] * acc[m][3][r];
#pragma unroll
              for (int msk = 1; msk < 16; msk <<= 1) {
                s  += __shfl_xor(s, msk, 64);
                s2 += __shfl_xor(s2, msk, 64);
              }
              float mean = s * (1.0f / 64.0f);
              float var  = s2 * (1.0f / 64.0f) - mean * mean;
              mu[r] = mean;
              rs[r] = rsqrtf(var + 1e-5f);
            }
          }
          int n0 = wm * 128 + m * 16 + rsub;
#pragma unroll
          for (int fn = 0; fn < 4; ++fn) {
            int dd = fn * 16 + dlane;
            bf16x4 pk;
#pragma unroll
            for (int r = 0; r < 4; ++r) {
              float xv = isK ? ((acc[m][fn][r] - mu[r]) * rs[r] * g4[fn] + b4[fn])
                             : acc[m][fn][r];
              pk[r] = (bf16)xv;
            }
            int blk = (n0 >> 2) ^ ((dd & 7) << 1);
            *(bf16x4*)(reg + dd * 512 + blk * 8) = pk;
          }
        }
      }
      LGKM0;
      BAR;
      // dots for head 2hp+rnd: all 8 waves
      const char* Abase = (char*)lds + 32768;   // vT (e rows)
      const char* Bbase = (char*)lds;           // kT (dk rows)
      f32x4 dacc[2] = {};
#pragma unroll
      for (int t8 = 0; t8 < 8; ++t8) {
        int blkb = t8 * 8 + (lane >> 4) * 2;
        int rA = qd * 16 + dlane;
        bf16x8 va = *(const bf16x8*)(Abase + rA * 512 + (blkb ^ ((rA & 7) << 1)) * 8);
#pragma unroll
        for (int j = 0; j < 2; ++j) {
          int rB = jh * 32 + j * 16 + dlane;
          bf16x8 vb = *(const bf16x8*)(Bbase + rB * 512 + (blkb ^ ((rB & 7) << 1)) * 8);
          dacc[j] = mfma_bf16_16x16x32(va, vb, dacc[j]);
        }
      }
      int bh = (tm >> 4) * 8 + 2 * hp + rnd;
      float* outp = dTp + ((size_t)bh * 16 + (tm & 15)) * 4096;
#pragma unroll
      for (int j = 0; j < 2; ++j)
#pragma unroll
        for (int r = 0; r < 4; ++r) {
          int e = qd * 16 + (lane >> 4) * 4 + r;
          outp[e * 64 + jh * 32 + j * 16 + dlane] = dacc[j][r];
        }
      if (rnd == 0) { LGKM0; BAR; }   // reads drained before round-1 overwrites
    }
  }
}

// ---------------- reduce 16 dots partials, cast to bf16 ----------------
__global__ __launch_bounds__(256) void k_cvt_dt(const float* __restrict__ dTp,
                                                bf16* __restrict__ dTb) {
  int j = blockIdx.x * 256 + threadIdx.x;   // 262144 = 64 bh * 4096
  int bh = j >> 12;
  int i = j & 4095;
  const float* p = dTp + (size_t)bh * 65536 + i;
  float s = 0.f;
#pragma unroll
  for (int c = 0; c < 16; ++c) s += p[c * 4096];
  dTb[j] = (bf16)s;
}

// ---------------- out = (Q @ dots) / n ----------------
__global__ __launch_bounds__(256) void k_out(const bf16* __restrict__ qh,
                                             const bf16* __restrict__ dTb,
                                             float* __restrict__ out) {
  __shared__ bf16 lA[128 * 64];
  const int tid = threadIdx.x, lane = tid & 63, w = tid >> 6;
  const int wm = w >> 1, wn = w & 1;
  const int bh = blockIdx.y, mt = blockIdx.x;
  const int bb = bh >> 3, h = bh & 7;
  const bf16* Ab = qh + (size_t)bh * 4096 * 64 + (size_t)mt * 128 * 64;
  const int srow = lane >> 3, sblk = (lane & 7) ^ srow;
#pragma unroll
  for (int i = 0; i < 4; ++i) {
    int slot = w * 4 + i;
    int row = slot * 8 + srow;
    gld_lds16(Ab + (size_t)row * 64 + sblk * 8, (char*)lA + slot * 1024);
  }
  __syncthreads();
  const bf16* Bb = dTb + (size_t)bh * 4096;
  f32x4 acc[4][2] = {};
#pragma unroll
  for (int ks = 0; ks < 2; ++ks) {
    bf16x8 af[4], bq[2];
#pragma unroll
    for (int f = 0; f < 4; ++f) {
      int row = wm * 64 + f * 16 + (lane & 15);
      int sb = (ks * 4 + (lane >> 4)) ^ (row & 7);
      af[f] = *(const bf16x8*)(lA + row * 64 + sb * 8);
    }
#pragma unroll
    for (int fn = 0; fn < 2; ++fn) {
      int e = wn * 32 + fn * 16 + (lane & 15);
      bq[fn] = *(const bf16x8*)(Bb + e * 64 + ks * 32 + (lane >> 4) * 8);
    }
#pragma unroll
    for (int fm = 0; fm < 4; ++fm)
#pragma unroll
      for (int fn = 0; fn < 2; ++fn)
        acc[fm][fn] = mfma_bf16_16x16x32(af[fm], bq[fn], acc[fm][fn]);
  }
#pragma unroll
  for (int fm = 0; fm < 4; ++fm)
#pragma unroll
    for (int fn = 0; fn < 2; ++fn)
#pragma unroll
      for (int r = 0; r < 4; ++r) {
        int n = mt * 128 + wm * 64 + fm * 16 + (lane >> 4) * 4 + r;
        int e = wn * 32 + fn * 16 + (lane & 15);
        out[((size_t)bb * 4096 + n) * 512 + h * 64 + e] = acc[fm][fn][r] * (1.0f / 4096.0f);
      }
}

extern "C" void kernel_launch(void* const* d_in, const int* in_sizes, int n_in,
                              void* d_out, int out_size, void* d_ws, size_t ws_size,
                              hipStream_t stream) {
  const float* x  = (const float*)d_in[0];
  const float* wq = (const float*)d_in[1];
  const float* qg = (const float*)d_in[2];
  const float* qb = (const float*)d_in[3];
  const float* kg = (const float*)d_in[4];
  const float* kb = (const float*)d_in[5];
  float* out = (float*)d_out;
  char* ws = (char*)d_ws;

  bf16* xb  = (bf16*)(ws);                          // 32 MB  [32768][512]
  bf16* wT  = (bf16*)(ws + ((size_t)32 << 20));     // 1.5 MB [1536][512] permuted
  bf16* qh  = (bf16*)(ws + ((size_t)34 << 20));     // 32 MB  [64][4096][64]
  float* dTp = (float*)(ws + ((size_t)66 << 20));   // 16.8 MB [64][16][4096]
  bf16* dTb  = (bf16*)(ws + ((size_t)83 << 20));    // 0.5 MB

  k_cast_x<<<8192, 256, 0, stream>>>(x, xb);
  k_prep_w<<<3072, 256, 0, stream>>>(wq, wT);
  k_qkv_gemm<<<768, 512, 65536, stream>>>(xb, wT, qg, qb, kg, kb, qh, dTp);
  k_cvt_dt<<<1024, 256, 0, stream>>>(dTp, dTb);
  k_out<<<dim3(32, 64), 256, 0, stream>>>(qh, dTb, out);
}

// Round 10
// 140.610 us; speedup vs baseline: 1.1509x; 1.1509x over previous
//
#include <hip/hip_runtime.h>
#include <hip/hip_bf16.h>
#include <stdint.h>

typedef __bf16 bf16;
typedef __bf16 bf16x8 __attribute__((ext_vector_type(8)));
typedef __bf16 bf16x4 __attribute__((ext_vector_type(4)));
typedef float  f32x4  __attribute__((ext_vector_type(4)));
typedef unsigned int u32;

typedef __attribute__((address_space(1))) u32 gu32;
typedef __attribute__((address_space(3))) u32 lu32;

__device__ __forceinline__ void gld_lds16(const void* g, void* l) {
  __builtin_amdgcn_global_load_lds((gu32*)(uintptr_t)g, (lu32*)(u32)(uintptr_t)l, 16, 0, 0);
}

__device__ __forceinline__ f32x4 mfma_bf16_16x16x32(bf16x8 a, bf16x8 b, f32x4 c) {
  return __builtin_amdgcn_mfma_f32_16x16x32_bf16(a, b, c, 0, 0, 0);
}

#define LGKM(n) do { asm volatile("s_waitcnt lgkmcnt(" #n ")" ::: "memory"); \
                     __builtin_amdgcn_sched_barrier(0); } while (0)
#define VMC(n) do { asm volatile("s_waitcnt vmcnt(" #n ")" ::: "memory"); } while (0)
#define BAR __builtin_amdgcn_s_barrier()
#define PRIO1 __builtin_amdgcn_s_setprio(1)
#define PRIO0 __builtin_amdgcn_s_setprio(0)

// ---------------- cast x (fp32 -> bf16), 8 elems/thread ----------------
__global__ __launch_bounds__(256) void k_cast_x(const float* __restrict__ x,
                                                bf16* __restrict__ xb) {
  size_t i = (size_t)blockIdx.x * 256 + threadIdx.x;
  const float4* p = (const float4*)x + i * 2;
  float4 a = p[0], b = p[1];
  bf16x8 o;
  o[0] = (bf16)a.x; o[1] = (bf16)a.y; o[2] = (bf16)a.z; o[3] = (bf16)a.w;
  o[4] = (bf16)b.x; o[5] = (bf16)b.y; o[6] = (bf16)b.z; o[7] = (bf16)b.w;
  *(bf16x8*)(xb + i * 8) = o;
}

// -------- transpose + PERMUTE w [512][1536] f32 -> wT [1536][512] bf16 --------
// kv tile hp (wT rows 512+hp*256..+255) = [k_{2hp} | k_{2hp+1} | v_{2hp} | v_{2hp+1}].
__global__ __launch_bounds__(256) void k_prep_w(const float* __restrict__ w,
                                                bf16* __restrict__ wT) {
  int idx = blockIdx.x * 256 + threadIdx.x;
  int r = idx >> 9;
  int k = idx & 511;
  int c;
  if (r < 512) {
    c = r;
  } else {
    int rr = r - 512;
    int hp = rr >> 8;
    int q2 = (rr >> 6) & 3;
    int d = r & 63;
    int h = 2 * hp + (q2 & 1);
    c = ((q2 < 2) ? 512 : 1024) + h * 64 + d;
  }
  wT[idx] = (bf16)w[k * 1536 + c];
}

template <int MH, int NH>
__device__ __forceinline__ void mm(f32x4 (&acc)[8][4],
                                   const bf16x8 (&a)[4][2],
                                   const bf16x8 (&b)[2][2]) {
#pragma unroll
  for (int fm = 0; fm < 4; ++fm)
#pragma unroll
    for (int fn = 0; fn < 2; ++fn)
#pragma unroll
      for (int ks = 0; ks < 2; ++ks)
        acc[MH * 4 + fm][NH * 2 + fn] =
            mfma_bf16_16x16x32(a[fm][ks], b[fn][ks], acc[MH * 4 + fm][NH * 2 + fn]);
}

// ---------------- QKV GEMM: phase-pipelined frag reads (counted lgkm) ----------
// LDS 128KB: A dbuf [0,64K), B dbuf [64K,128K).  Per step t (buf d=t&1):
//  P0: read B1(d)[4]; stage A(d^1,t+1)[4 glds]; lgkm(4) -> MFMA<0,0>; BAR
//  P1: read A1(d)[8]; stage B(d^1,t+1)[4 glds]; lgkm(8) -> MFMA<0,1>; BAR
//  P2: vmcnt(0); BAR(publish t+1); lgkm(0) -> MFMA<1,0>; BAR
//  P3: read A0,B0(d^1,t+1)[12] (overlap); MFMA<1,1>; BAR
// Every lgkm wait covers only reads issued >=1 phase earlier -> LDS/MFMA overlap.
__global__ __launch_bounds__(512, 2) void k_qkv_gemm(
    const bf16* __restrict__ A, const bf16* __restrict__ Bt,
    const float* __restrict__ qg, const float* __restrict__ qbeta,
    const float* __restrict__ kg, const float* __restrict__ kbeta,
    bf16* __restrict__ qh, float* __restrict__ dTp)
{
  extern __shared__ bf16 lds[];
  const int tid = threadIdx.x;
  const int lane = tid & 63;
  const int w = tid >> 6;        // 0..7
  const int wm = w >> 2;         // 0..1
  const int wn = w & 3;          // 0..3

  const int wg = blockIdx.x;
  const int swz = (wg & 7) * 96 + (wg >> 3);
  const int tn = swz % 6;
  const int tm = swz / 6;

  auto stA = [&](int buf, int slot, int ktile) {
#pragma unroll
    for (int i = 0; i < 2; ++i) {
      int vr = i * 64 + w * 8 + (lane >> 3);
      int grow = tm * 256 + (vr >> 6) * 128 + slot * 64 + (vr & 63);
      int gk = ktile * 64 + (((lane & 7) ^ (vr & 7)) * 8);
      gld_lds16(A + (size_t)grow * 512 + gk,
                (char*)lds + buf * 32768 + slot * 16384 + i * 8192 + w * 1024);
    }
  };
  auto stB = [&](int buf, int slot, int ktile) {
#pragma unroll
    for (int i = 0; i < 2; ++i) {
      int vr = i * 64 + w * 8 + (lane >> 3);
      int grow = tn * 256 + (vr >> 5) * 64 + slot * 32 + (vr & 31);
      int gk = ktile * 64 + (((lane & 7) ^ (vr & 7)) * 8);
      gld_lds16(Bt + (size_t)grow * 512 + gk,
                (char*)lds + 65536 + buf * 32768 + slot * 16384 + i * 8192 + w * 1024);
    }
  };
  auto rdA = [&](int buf, int mh, bf16x8 (&fr)[4][2]) {
    const bf16* base = lds + buf * 16384 + mh * 8192;
#pragma unroll
    for (int f = 0; f < 4; ++f) {
      int vr = wm * 64 + f * 16 + (lane & 15);
#pragma unroll
      for (int ks = 0; ks < 2; ++ks) {
        int pb = (ks * 4 + (lane >> 4)) ^ (vr & 7);
        fr[f][ks] = *(const bf16x8*)(base + vr * 64 + pb * 8);
      }
    }
  };
  auto rdB = [&](int buf, int nh, bf16x8 (&fr)[2][2]) {
    const bf16* base = lds + 32768 + buf * 16384 + nh * 8192;
#pragma unroll
    for (int f = 0; f < 2; ++f) {
      int vr = wn * 32 + f * 16 + (lane & 15);
#pragma unroll
      for (int ks = 0; ks < 2; ++ks) {
        int pb = (ks * 4 + (lane >> 4)) ^ (vr & 7);
        fr[f][ks] = *(const bf16x8*)(base + vr * 64 + pb * 8);
      }
    }
  };

  bf16x8 afr0[4][2], afr1[4][2];
  bf16x8 bfr0[2][2], bfr1[2][2];
  f32x4 acc[8][4];
  {
    f32x4 z = {0.f, 0.f, 0.f, 0.f};
#pragma unroll
    for (int m = 0; m < 8; ++m)
#pragma unroll
      for (int n = 0; n < 4; ++n) acc[m][n] = z;
  }

  // ---- prologue: stage tile 0 into buf0; read step0's A0,B0 frags ----
  stA(0, 0, 0); stA(0, 1, 0); stB(0, 0, 0); stB(0, 1, 0);
  VMC(0);
  BAR;
  rdA(0, 0, afr0); rdB(0, 0, bfr0);   // 12 reads, waited at P0's lgkm(4)

#pragma unroll
  for (int t = 0; t < 8; ++t) {
    const int d = t & 1;
    // ---- P0: read B1; stage A(t+1); lgkm(4) covers prologue/P3 reads
    rdB(d, 1, bfr1);
    if (t < 7) { stA(d ^ 1, 0, t + 1); stA(d ^ 1, 1, t + 1); }
    LGKM(4);
    PRIO1; mm<0, 0>(acc, afr0, bfr0); PRIO0;
    BAR;
    // ---- P1: read A1; stage B(t+1); lgkm(8) covers B1
    rdA(d, 1, afr1);
    if (t < 7) { stB(d ^ 1, 0, t + 1); stB(d ^ 1, 1, t + 1); }
    LGKM(8);
    PRIO1; mm<0, 1>(acc, afr0, bfr1); PRIO0;
    BAR;
    // ---- P2: publish t+1 staging; lgkm(0) covers A1
    if (t < 7) VMC(0);
    BAR;
    LGKM(0);
    PRIO1; mm<1, 0>(acc, afr1, bfr0); PRIO0;
    BAR;
    // ---- P3: read next step's A0,B0 (overlaps MFMA<1,1>)
    if (t < 7) { rdA(d ^ 1, 0, afr0); rdB(d ^ 1, 0, bfr0); }
    PRIO1; mm<1, 1>(acc, afr1, bfr1); PRIO0;
    BAR;
  }

  const int dlane = lane & 15;
  const int rsub = (lane >> 4) * 4;

  if (tn < 2) {
    // ---- q epilogue: LN + store [bh][n][d] ----
    const int hcol = tn * 4 + wn;
    float g4[4], b4[4];
#pragma unroll
    for (int fn = 0; fn < 4; ++fn) {
      g4[fn] = qg[fn * 16 + dlane];
      b4[fn] = qbeta[fn * 16 + dlane];
    }
#pragma unroll
    for (int m = 0; m < 8; ++m) {
      float mu[4], rs[4];
#pragma unroll
      for (int r = 0; r < 4; ++r) {
        float s  = acc[m][0][r] + acc[m][1][r] + acc[m][2][r] + acc[m][3][r];
        float s2 = acc[m][0][r] * acc[m][0][r] + acc[m][1][r] * acc[m][1][r]
                 + acc[m][2][r] * acc[m][2][r] + acc[m][3][r] * acc[m][3][r];
#pragma unroll
        for (int msk = 1; msk < 16; msk <<= 1) {
          s  += __shfl_xor(s, msk, 64);
          s2 += __shfl_xor(s2, msk, 64);
        }
        float mean = s * (1.0f / 64.0f);
        float var  = s2 * (1.0f / 64.0f) - mean * mean;
        mu[r] = mean;
        rs[r] = rsqrtf(var + 1e-5f);
      }
      int rowg = tm * 256 + wm * 128 + m * 16 + rsub;
      int bb2 = rowg >> 12, n0 = rowg & 4095;
      int bh = bb2 * 8 + hcol;
      bf16* dst = qh + ((size_t)bh * 4096 + n0) * 64;
#pragma unroll
      for (int r = 0; r < 4; ++r)
#pragma unroll
        for (int fn = 0; fn < 4; ++fn) {
          float xv = (acc[m][fn][r] - mu[r]) * rs[r] * g4[fn] + b4[fn];
          dst[(size_t)r * 64 + fn * 16 + dlane] = (bf16)xv;
        }
    }
  } else {
    // ---- kv epilogue: two rounds (one head each) in first 64KB of LDS ----
    const int hp = tn - 2;
    const bool isK = (wn < 2);
    const int hloc = wn & 1;
    char* reg = (char*)lds + (isK ? 0 : 32768);
    float g4[4], b4[4];
    if (isK) {
#pragma unroll
      for (int fn = 0; fn < 4; ++fn) {
        g4[fn] = kg[fn * 16 + dlane];
        b4[fn] = kbeta[fn * 16 + dlane];
      }
    }
    const int qd = w & 3;        // e-row group
    const int jh = w >> 2;       // dk half
#pragma unroll
    for (int rnd = 0; rnd < 2; ++rnd) {
      if (hloc == rnd) {
#pragma unroll
        for (int m = 0; m < 8; ++m) {
          float mu[4] = {}, rs[4] = {};
          if (isK) {
#pragma unroll
            for (int r = 0; r < 4; ++r) {
              float s  = acc[m][0][r] + acc[m][1][r] + acc[m][2][r] + acc[m][3][r];
              float s2 = acc[m][0][r] * acc[m][0][r] + acc[m][1][r] * acc[m][1][r]
                       + acc[m][2][r] * acc[m][2][r] + acc[m][3][r] * acc[m][3][r];
#pragma unroll
              for (int msk = 1; msk < 16; msk <<= 1) {
                s  += __shfl_xor(s, msk, 64);
                s2 += __shfl_xor(s2, msk, 64);
              }
              float mean = s * (1.0f / 64.0f);
              float var  = s2 * (1.0f / 64.0f) - mean * mean;
              mu[r] = mean;
              rs[r] = rsqrtf(var + 1e-5f);
            }
          }
          int n0 = wm * 128 + m * 16 + rsub;
#pragma unroll
          for (int fn = 0; fn < 4; ++fn) {
            int dd = fn * 16 + dlane;
            bf16x4 pk;
#pragma unroll
            for (int r = 0; r < 4; ++r) {
              float xv = isK ? ((acc[m][fn][r] - mu[r]) * rs[r] * g4[fn] + b4[fn])
                             : acc[m][fn][r];
              pk[r] = (bf16)xv;
            }
            int blk = (n0 >> 2) ^ ((dd & 7) << 1);
            *(bf16x4*)(reg + dd * 512 + blk * 8) = pk;
          }
        }
      }
      LGKM(0);
      BAR;
      const char* Abase = (char*)lds + 32768;   // vT (e rows)
      const char* Bbase = (char*)lds;           // kT (dk rows)
      f32x4 dacc[2] = {};
#pragma unroll
      for (int t8 = 0; t8 < 8; ++t8) {
        int blkb = t8 * 8 + (lane >> 4) * 2;
        int rA = qd * 16 + dlane;
        bf16x8 va = *(const bf16x8*)(Abase + rA * 512 + (blkb ^ ((rA & 7) << 1)) * 8);
#pragma unroll
        for (int j = 0; j < 2; ++j) {
          int rB = jh * 32 + j * 16 + dlane;
          bf16x8 vb = *(const bf16x8*)(Bbase + rB * 512 + (blkb ^ ((rB & 7) << 1)) * 8);
          dacc[j] = mfma_bf16_16x16x32(va, vb, dacc[j]);
        }
      }
      int bh = (tm >> 4) * 8 + 2 * hp + rnd;
      float* outp = dTp + ((size_t)bh * 16 + (tm & 15)) * 4096;
#pragma unroll
      for (int j = 0; j < 2; ++j)
#pragma unroll
        for (int r = 0; r < 4; ++r) {
          int e = qd * 16 + (lane >> 4) * 4 + r;
          outp[e * 64 + jh * 32 + j * 16 + dlane] = dacc[j][r];
        }
      if (rnd == 0) { LGKM(0); BAR; }
    }
  }
}

// ---------------- reduce 16 dots partials, cast to bf16 ----------------
__global__ __launch_bounds__(256) void k_cvt_dt(const float* __restrict__ dTp,
                                                bf16* __restrict__ dTb) {
  int j = blockIdx.x * 256 + threadIdx.x;   // 262144 = 64 bh * 4096
  int bh = j >> 12;
  int i = j & 4095;
  const float* p = dTp + (size_t)bh * 65536 + i;
  float s = 0.f;
#pragma unroll
  for (int c = 0; c < 16; ++c) s += p[c * 4096];
  dTb[j] = (bf16)s;
}

// ---------------- out = (Q @ dots) / n ----------------
__global__ __launch_bounds__(256) void k_out(const bf16* __restrict__ qh,
                                             const bf16* __restrict__ dTb,
                                             float* __restrict__ out) {
  __shared__ bf16 lA[128 * 64];
  const int tid = threadIdx.x, lane = tid & 63, w = tid >> 6;
  const int wm = w >> 1, wn = w & 1;
  const int bh = blockIdx.y, mt = blockIdx.x;
  const int bb = bh >> 3, h = bh & 7;
  const bf16* Ab = qh + (size_t)bh * 4096 * 64 + (size_t)mt * 128 * 64;
  const int srow = lane >> 3, sblk = (lane & 7) ^ srow;
#pragma unroll
  for (int i = 0; i < 4; ++i) {
    int slot = w * 4 + i;
    int row = slot * 8 + srow;
    gld_lds16(Ab + (size_t)row * 64 + sblk * 8, (char*)lA + slot * 1024);
  }
  __syncthreads();
  const bf16* Bb = dTb + (size_t)bh * 4096;
  f32x4 acc[4][2] = {};
#pragma unroll
  for (int ks = 0; ks < 2; ++ks) {
    bf16x8 af[4], bq[2];
#pragma unroll
    for (int f = 0; f < 4; ++f) {
      int row = wm * 64 + f * 16 + (lane & 15);
      int sb = (ks * 4 + (lane >> 4)) ^ (row & 7);
      af[f] = *(const bf16x8*)(lA + row * 64 + sb * 8);
    }
#pragma unroll
    for (int fn = 0; fn < 2; ++fn) {
      int e = wn * 32 + fn * 16 + (lane & 15);
      bq[fn] = *(const bf16x8*)(Bb + e * 64 + ks * 32 + (lane >> 4) * 8);
    }
#pragma unroll
    for (int fm = 0; fm < 4; ++fm)
#pragma unroll
      for (int fn = 0; fn < 2; ++fn)
        acc[fm][fn] = mfma_bf16_16x16x32(af[fm], bq[fn], acc[fm][fn]);
  }
#pragma unroll
  for (int fm = 0; fm < 4; ++fm)
#pragma unroll
    for (int fn = 0; fn < 2; ++fn)
#pragma unroll
      for (int r = 0; r < 4; ++r) {
        int n = mt * 128 + wm * 64 + fm * 16 + (lane >> 4) * 4 + r;
        int e = wn * 32 + fn * 16 + (lane & 15);
        out[((size_t)bb * 4096 + n) * 512 + h * 64 + e] = acc[fm][fn][r] * (1.0f / 4096.0f);
      }
}

extern "C" void kernel_launch(void* const* d_in, const int* in_sizes, int n_in,
                              void* d_out, int out_size, void* d_ws, size_t ws_size,
                              hipStream_t stream) {
  const float* x  = (const float*)d_in[0];
  const float* wq = (const float*)d_in[1];
  const float* qg = (const float*)d_in[2];
  const float* qb = (const float*)d_in[3];
  const float* kg = (const float*)d_in[4];
  const float* kb = (const float*)d_in[5];
  float* out = (float*)d_out;
  char* ws = (char*)d_ws;

  bf16* xb  = (bf16*)(ws);                          // 32 MB  [32768][512]
  bf16* wT  = (bf16*)(ws + ((size_t)32 << 20));     // 1.5 MB [1536][512] permuted
  bf16* qh  = (bf16*)(ws + ((size_t)34 << 20));     // 32 MB  [64][4096][64]
  float* dTp = (float*)(ws + ((size_t)66 << 20));   // 16.8 MB [64][16][4096]
  bf16* dTb  = (bf16*)(ws + ((size_t)83 << 20));    // 0.5 MB

  k_cast_x<<<8192, 256, 0, stream>>>(x, xb);
  k_prep_w<<<3072, 256, 0, stream>>>(wq, wT);
  k_qkv_gemm<<<768, 512, 131072, stream>>>(xb, wT, qg, qb, kg, kb, qh, dTp);
  k_cvt_dt<<<1024, 256, 0, stream>>>(dTp, dTb);
  k_out<<<dim3(32, 64), 256, 0, stream>>>(qh, dTb, out);
}

// Round 11
// 123.710 us; speedup vs baseline: 1.3081x; 1.1366x over previous
//
#include <hip/hip_runtime.h>
#include <hip/hip_bf16.h>
#include <stdint.h>

typedef __bf16 bf16;
typedef __bf16 bf16x8 __attribute__((ext_vector_type(8)));
typedef __bf16 bf16x4 __attribute__((ext_vector_type(4)));
typedef float  f32x4  __attribute__((ext_vector_type(4)));
typedef unsigned int u32;

typedef __attribute__((address_space(1))) u32 gu32;
typedef __attribute__((address_space(3))) u32 lu32;

__device__ __forceinline__ void gld_lds16(const void* g, void* l) {
  __builtin_amdgcn_global_load_lds((gu32*)(uintptr_t)g, (lu32*)(u32)(uintptr_t)l, 16, 0, 0);
}

__device__ __forceinline__ f32x4 mfma_bf16_16x16x32(bf16x8 a, bf16x8 b, f32x4 c) {
  return __builtin_amdgcn_mfma_f32_16x16x32_bf16(a, b, c, 0, 0, 0);
}

#define LGKM0 do { asm volatile("s_waitcnt lgkmcnt(0)" ::: "memory"); \
                   __builtin_amdgcn_sched_barrier(0); } while (0)
#define VMC0 do { asm volatile("s_waitcnt vmcnt(0)" ::: "memory"); } while (0)
#define BAR __builtin_amdgcn_s_barrier()

// ---------------- cast x (fp32 -> bf16), 8 elems/thread ----------------
__global__ __launch_bounds__(256) void k_cast_x(const float* __restrict__ x,
                                                bf16* __restrict__ xb) {
  size_t i = (size_t)blockIdx.x * 256 + threadIdx.x;
  const float4* p = (const float4*)x + i * 2;
  float4 a = p[0], b = p[1];
  bf16x8 o;
  o[0] = (bf16)a.x; o[1] = (bf16)a.y; o[2] = (bf16)a.z; o[3] = (bf16)a.w;
  o[4] = (bf16)b.x; o[5] = (bf16)b.y; o[6] = (bf16)b.z; o[7] = (bf16)b.w;
  *(bf16x8*)(xb + i * 8) = o;
}

// -------- transpose + PERMUTE w [512][1536] f32 -> wT [1536][512] bf16 --------
// q: wT rows 0-511 = q cols 0-511 (tiles tn 0-3).
// kv tile tn=4+h (rows 512+h*128 .. +127): first 64 rows = k_h, next 64 = v_h.
__global__ __launch_bounds__(256) void k_prep_w(const float* __restrict__ w,
                                                bf16* __restrict__ wT) {
  int idx = blockIdx.x * 256 + threadIdx.x;
  int r = idx >> 9;
  int k = idx & 511;
  int c;
  if (r < 512) {
    c = r;
  } else {
    int rr = r - 512;
    int h = rr >> 7;
    int half = (rr >> 6) & 1;
    int d = r & 63;
    c = (half == 0 ? 512 : 1024) + h * 64 + d;
  }
  wT[idx] = (bf16)w[k * 1536 + c];
}

// ---------------- QKV GEMM: 128x128 tile, BK=64, 4 waves, 64KB LDS ------------
// m97 regime: 2 blocks/CU; 1 barrier + vmcnt(0) per K-step; compiler lgkm waits.
// Epilogue: q tiles (tn<4) -> LN + store qh; kv tiles (tn=4+h) -> k-LN/v to LDS
// then 64x64 dots partial over this block's 128 rows -> dTp[bh][tm&31][.].
__global__ __launch_bounds__(256, 2) void k_qkv_gemm(
    const bf16* __restrict__ A, const bf16* __restrict__ Bt,
    const float* __restrict__ qg, const float* __restrict__ qbeta,
    const float* __restrict__ kg, const float* __restrict__ kbeta,
    bf16* __restrict__ qh, float* __restrict__ dTp)
{
  extern __shared__ bf16 lds[];   // A: buf*8192 elems; B: 16384 + buf*8192
  const int tid = threadIdx.x;
  const int lane = tid & 63;
  const int w = tid >> 6;        // 0..3
  const int wm = w >> 1;         // 0..1
  const int wn = w & 1;          // 0..1

  // XCD swizzle: 3072 = 8 x 384; 12 consecutive per XCD share tm (A panel L2-hot)
  const int wg = blockIdx.x;
  const int swz = (wg & 7) * 384 + (wg >> 3);
  const int tn = swz % 12;
  const int tm = swz / 12;

  auto stA = [&](int buf, int ktile) {
#pragma unroll
    for (int i = 0; i < 4; ++i) {
      int vr = i * 32 + w * 8 + (lane >> 3);
      int gk = ktile * 64 + (((lane & 7) ^ (vr & 7)) * 8);
      gld_lds16(A + (size_t)(tm * 128 + vr) * 512 + gk,
                (char*)lds + buf * 16384 + i * 4096 + w * 1024);
    }
  };
  auto stB = [&](int buf, int ktile) {
#pragma unroll
    for (int i = 0; i < 4; ++i) {
      int vr = i * 32 + w * 8 + (lane >> 3);
      int gk = ktile * 64 + (((lane & 7) ^ (vr & 7)) * 8);
      gld_lds16(Bt + (size_t)(tn * 128 + vr) * 512 + gk,
                (char*)lds + 32768 + buf * 16384 + i * 4096 + w * 1024);
    }
  };
  auto rdA = [&](int buf, bf16x8 (&fr)[4][2]) {
    const bf16* base = lds + buf * 8192;
#pragma unroll
    for (int f = 0; f < 4; ++f) {
      int vr = wm * 64 + f * 16 + (lane & 15);
#pragma unroll
      for (int ks = 0; ks < 2; ++ks) {
        int pb = (ks * 4 + (lane >> 4)) ^ (vr & 7);
        fr[f][ks] = *(const bf16x8*)(base + vr * 64 + pb * 8);
      }
    }
  };
  auto rdB = [&](int buf, bf16x8 (&fr)[4][2]) {
    const bf16* base = lds + 16384 + buf * 8192;
#pragma unroll
    for (int f = 0; f < 4; ++f) {
      int vr = wn * 64 + f * 16 + (lane & 15);
#pragma unroll
      for (int ks = 0; ks < 2; ++ks) {
        int pb = (ks * 4 + (lane >> 4)) ^ (vr & 7);
        fr[f][ks] = *(const bf16x8*)(base + vr * 64 + pb * 8);
      }
    }
  };

  bf16x8 af[4][2], bf[4][2];
  f32x4 acc[4][4];
  {
    f32x4 z = {0.f, 0.f, 0.f, 0.f};
#pragma unroll
    for (int m = 0; m < 4; ++m)
#pragma unroll
      for (int n = 0; n < 4; ++n) acc[m][n] = z;
  }

  // ---- prologue ----
  stA(0, 0); stB(0, 0);
  VMC0; BAR;

#pragma unroll
  for (int t = 0; t < 8; ++t) {
    const int d = t & 1;
    if (t < 7) { stA(d ^ 1, t + 1); stB(d ^ 1, t + 1); }
    rdA(d, af); rdB(d, bf);
#pragma unroll
    for (int fm = 0; fm < 4; ++fm)
#pragma unroll
      for (int fn = 0; fn < 4; ++fn)
#pragma unroll
        for (int ks = 0; ks < 2; ++ks)
          acc[fm][fn] = mfma_bf16_16x16x32(af[fm][ks], bf[fn][ks], acc[fm][fn]);
    if (t < 7) VMC0;
    BAR;
  }

  const int dlane = lane & 15;
  const int rsub = (lane >> 4) * 4;

  if (tn < 4) {
    // ---- q epilogue: LN + store [bh][n][d] ----
    const int hcol = tn * 2 + wn;    // head 0..7
    float g4[4], b4[4];
#pragma unroll
    for (int fn = 0; fn < 4; ++fn) {
      g4[fn] = qg[fn * 16 + dlane];
      b4[fn] = qbeta[fn * 16 + dlane];
    }
#pragma unroll
    for (int m = 0; m < 4; ++m) {
      float mu[4], rs[4];
#pragma unroll
      for (int r = 0; r < 4; ++r) {
        float s  = acc[m][0][r] + acc[m][1][r] + acc[m][2][r] + acc[m][3][r];
        float s2 = acc[m][0][r] * acc[m][0][r] + acc[m][1][r] * acc[m][1][r]
                 + acc[m][2][r] * acc[m][2][r] + acc[m][3][r] * acc[m][3][r];
#pragma unroll
        for (int msk = 1; msk < 16; msk <<= 1) {
          s  += __shfl_xor(s, msk, 64);
          s2 += __shfl_xor(s2, msk, 64);
        }
        float mean = s * (1.0f / 64.0f);
        float var  = s2 * (1.0f / 64.0f) - mean * mean;
        mu[r] = mean;
        rs[r] = rsqrtf(var + 1e-5f);
      }
      int rowg = tm * 128 + wm * 64 + m * 16 + rsub;
      int bb2 = rowg >> 12, n0 = rowg & 4095;
      int bh = bb2 * 8 + hcol;
      bf16* dst = qh + ((size_t)bh * 4096 + n0) * 64;
#pragma unroll
      for (int r = 0; r < 4; ++r)
#pragma unroll
        for (int fn = 0; fn < 4; ++fn) {
          float xv = (acc[m][fn][r] - mu[r]) * rs[r] * g4[fn] + b4[fn];
          dst[(size_t)r * 64 + fn * 16 + dlane] = (bf16)xv;
        }
    }
  } else {
    // ---- kv epilogue: wn=0 -> k_h (LN), wn=1 -> v_h; LDS [d][n] swizzled ----
    const int h = tn - 4;
    const bool isK = (wn == 0);
    char* reg = (char*)lds + (isK ? 0 : 16384);   // kT @0, vT @16KB (64 d x 128 n)
    float g4[4], b4[4];
    if (isK) {
#pragma unroll
      for (int fn = 0; fn < 4; ++fn) {
        g4[fn] = kg[fn * 16 + dlane];
        b4[fn] = kbeta[fn * 16 + dlane];
      }
    }
#pragma unroll
    for (int m = 0; m < 4; ++m) {
      float mu[4] = {}, rs[4] = {};
      if (isK) {
#pragma unroll
        for (int r = 0; r < 4; ++r) {
          float s  = acc[m][0][r] + acc[m][1][r] + acc[m][2][r] + acc[m][3][r];
          float s2 = acc[m][0][r] * acc[m][0][r] + acc[m][1][r] * acc[m][1][r]
                   + acc[m][2][r] * acc[m][2][r] + acc[m][3][r] * acc[m][3][r];
#pragma unroll
          for (int msk = 1; msk < 16; msk <<= 1) {
            s  += __shfl_xor(s, msk, 64);
            s2 += __shfl_xor(s2, msk, 64);
          }
          float mean = s * (1.0f / 64.0f);
          float var  = s2 * (1.0f / 64.0f) - mean * mean;
          mu[r] = mean;
          rs[r] = rsqrtf(var + 1e-5f);
        }
      }
      int n0 = wm * 64 + m * 16 + rsub;            // 0..127
#pragma unroll
      for (int fn = 0; fn < 4; ++fn) {
        int dd = fn * 16 + dlane;
        bf16x4 pk;
#pragma unroll
        for (int r = 0; r < 4; ++r) {
          float xv = isK ? ((acc[m][fn][r] - mu[r]) * rs[r] * g4[fn] + b4[fn])
                         : acc[m][fn][r];
          pk[r] = (bf16)xv;
        }
        int blk = (n0 >> 2) ^ ((dd & 7) << 1);     // 32 granules of 8B per d-row
        *(bf16x4*)(reg + dd * 256 + blk * 8) = pk;
      }
    }
    LGKM0;
    BAR;
    // ---- dots D[e][dk] = sum_{n<128} v[n][e] k[n][dk]; wave qd=w: e-rows qd*16.. ----
    const int qd = w;
    const char* vT = (char*)lds + 16384;
    const char* kT = (char*)lds;
    f32x4 dacc[4] = {};
#pragma unroll
    for (int ks = 0; ks < 4; ++ks) {               // K=128, 4 slices of 32
      int g0 = ks * 8 + (lane >> 4) * 2;           // granule base (even)
      int e = qd * 16 + dlane;
      bf16x8 va = *(const bf16x8*)(vT + e * 256 + (g0 ^ ((e & 7) << 1)) * 8);
#pragma unroll
      for (int j = 0; j < 4; ++j) {
        int dk = j * 16 + dlane;
        bf16x8 vb = *(const bf16x8*)(kT + dk * 256 + (g0 ^ ((dk & 7) << 1)) * 8);
        dacc[j] = mfma_bf16_16x16x32(va, vb, dacc[j]);
      }
    }
    int bh = (tm >> 5) * 8 + h;
    float* outp = dTp + ((size_t)bh * 32 + (tm & 31)) * 4096;
#pragma unroll
    for (int j = 0; j < 4; ++j)
#pragma unroll
      for (int r = 0; r < 4; ++r) {
        int e = qd * 16 + (lane >> 4) * 4 + r;
        outp[e * 64 + j * 16 + dlane] = dacc[j][r];
      }
  }
}

// ---------------- reduce 32 dots partials, cast to bf16 ----------------
__global__ __launch_bounds__(256) void k_cvt_dt(const float* __restrict__ dTp,
                                                bf16* __restrict__ dTb) {
  int j = blockIdx.x * 256 + threadIdx.x;   // 262144 = 64 bh * 4096
  int bh = j >> 12;
  int i = j & 4095;
  const float* p = dTp + (size_t)bh * 131072 + i;
  float s = 0.f;
#pragma unroll
  for (int c = 0; c < 32; ++c) s += p[c * 4096];
  dTb[j] = (bf16)s;
}

// ---------------- out = (Q @ dots) / n ----------------
__global__ __launch_bounds__(256) void k_out(const bf16* __restrict__ qh,
                                             const bf16* __restrict__ dTb,
                                             float* __restrict__ out) {
  __shared__ bf16 lA[128 * 64];
  const int tid = threadIdx.x, lane = tid & 63, w = tid >> 6;
  const int wm = w >> 1, wn = w & 1;
  const int bh = blockIdx.y, mt = blockIdx.x;
  const int bb = bh >> 3, h = bh & 7;
  const bf16* Ab = qh + (size_t)bh * 4096 * 64 + (size_t)mt * 128 * 64;
  const int srow = lane >> 3, sblk = (lane & 7) ^ srow;
#pragma unroll
  for (int i = 0; i < 4; ++i) {
    int slot = w * 4 + i;
    int row = slot * 8 + srow;
    gld_lds16(Ab + (size_t)row * 64 + sblk * 8, (char*)lA + slot * 1024);
  }
  __syncthreads();
  const bf16* Bb = dTb + (size_t)bh * 4096;
  f32x4 acc[4][2] = {};
#pragma unroll
  for (int ks = 0; ks < 2; ++ks) {
    bf16x8 af[4], bq[2];
#pragma unroll
    for (int f = 0; f < 4; ++f) {
      int row = wm * 64 + f * 16 + (lane & 15);
      int sb = (ks * 4 + (lane >> 4)) ^ (row & 7);
      af[f] = *(const bf16x8*)(lA + row * 64 + sb * 8);
    }
#pragma unroll
    for (int fn = 0; fn < 2; ++fn) {
      int e = wn * 32 + fn * 16 + (lane & 15);
      bq[fn] = *(const bf16x8*)(Bb + e * 64 + ks * 32 + (lane >> 4) * 8);
    }
#pragma unroll
    for (int fm = 0; fm < 4; ++fm)
#pragma unroll
      for (int fn = 0; fn < 2; ++fn)
        acc[fm][fn] = mfma_bf16_16x16x32(af[fm], bq[fn], acc[fm][fn]);
  }
#pragma unroll
  for (int fm = 0; fm < 4; ++fm)
#pragma unroll
    for (int fn = 0; fn < 2; ++fn)
#pragma unroll
      for (int r = 0; r < 4; ++r) {
        int n = mt * 128 + wm * 64 + fm * 16 + (lane >> 4) * 4 + r;
        int e = wn * 32 + fn * 16 + (lane & 15);
        out[((size_t)bb * 4096 + n) * 512 + h * 64 + e] = acc[fm][fn][r] * (1.0f / 4096.0f);
      }
}

extern "C" void kernel_launch(void* const* d_in, const int* in_sizes, int n_in,
                              void* d_out, int out_size, void* d_ws, size_t ws_size,
                              hipStream_t stream) {
  const float* x  = (const float*)d_in[0];
  const float* wq = (const float*)d_in[1];
  const float* qg = (const float*)d_in[2];
  const float* qb = (const float*)d_in[3];
  const float* kg = (const float*)d_in[4];
  const float* kb = (const float*)d_in[5];
  float* out = (float*)d_out;
  char* ws = (char*)d_ws;

  bf16* xb  = (bf16*)(ws);                          // 32 MB  [32768][512]
  bf16* wT  = (bf16*)(ws + ((size_t)32 << 20));     // 1.5 MB [1536][512] permuted
  bf16* qh  = (bf16*)(ws + ((size_t)34 << 20));     // 32 MB  [64][4096][64]
  float* dTp = (float*)(ws + ((size_t)66 << 20));   // 32 MB  [64][32][4096]
  bf16* dTb  = (bf16*)(ws + ((size_t)99 << 20));    // 0.5 MB

  k_cast_x<<<8192, 256, 0, stream>>>(x, xb);
  k_prep_w<<<3072, 256, 0, stream>>>(wq, wT);
  k_qkv_gemm<<<3072, 256, 65536, stream>>>(xb, wT, qg, qb, kg, kb, qh, dTp);
  k_cvt_dt<<<1024, 256, 0, stream>>>(dTp, dTb);
  k_out<<<dim3(32, 64), 256, 0, stream>>>(qh, dTb, out);
}

// Round 12
// 108.223 us; speedup vs baseline: 1.4953x; 1.1431x over previous
//
#include <hip/hip_runtime.h>
#include <hip/hip_bf16.h>
#include <stdint.h>

typedef __bf16 bf16;
typedef __bf16 bf16x8 __attribute__((ext_vector_type(8)));
typedef __bf16 bf16x4 __attribute__((ext_vector_type(4)));
typedef float  f32x4  __attribute__((ext_vector_type(4)));
typedef unsigned int u32;

typedef __attribute__((address_space(1))) u32 gu32;
typedef __attribute__((address_space(3))) u32 lu32;

__device__ __forceinline__ void gld_lds16(const void* g, void* l) {
  __builtin_amdgcn_global_load_lds((gu32*)(uintptr_t)g, (lu32*)(u32)(uintptr_t)l, 16, 0, 0);
}

__device__ __forceinline__ f32x4 mfma_bf16_16x16x32(bf16x8 a, bf16x8 b, f32x4 c) {
  return __builtin_amdgcn_mfma_f32_16x16x32_bf16(a, b, c, 0, 0, 0);
}

#define LGKM0 do { asm volatile("s_waitcnt lgkmcnt(0)" ::: "memory"); \
                   __builtin_amdgcn_sched_barrier(0); } while (0)
#define VMC(n) do { asm volatile("s_waitcnt vmcnt(" #n ")" ::: "memory"); } while (0)
#define BAR __builtin_amdgcn_s_barrier()
#define PRIO1 __builtin_amdgcn_s_setprio(1)
#define PRIO0 __builtin_amdgcn_s_setprio(0)

// -------- merged prep: blocks 0-8191 cast x (fp32->bf16, 8 elems/thread);
//          blocks 8192-11263 transpose+permute w -> wT bf16.
// kv tile hp (wT rows 512+hp*256..+255) = [k_{2hp} | k_{2hp+1} | v_{2hp} | v_{2hp+1}].
__global__ __launch_bounds__(256) void k_prep(const float* __restrict__ x,
                                              bf16* __restrict__ xb,
                                              const float* __restrict__ w,
                                              bf16* __restrict__ wT) {
  if (blockIdx.x < 8192) {
    size_t i = (size_t)blockIdx.x * 256 + threadIdx.x;
    const float4* p = (const float4*)x + i * 2;
    float4 a = p[0], b = p[1];
    bf16x8 o;
    o[0] = (bf16)a.x; o[1] = (bf16)a.y; o[2] = (bf16)a.z; o[3] = (bf16)a.w;
    o[4] = (bf16)b.x; o[5] = (bf16)b.y; o[6] = (bf16)b.z; o[7] = (bf16)b.w;
    *(bf16x8*)(xb + i * 8) = o;
  } else {
    int idx = (blockIdx.x - 8192) * 256 + threadIdx.x;
    int r = idx >> 9;
    int k = idx & 511;
    int c;
    if (r < 512) {
      c = r;
    } else {
      int rr = r - 512;
      int hp = rr >> 8;
      int q2 = (rr >> 6) & 3;
      int d = r & 63;
      int h = 2 * hp + (q2 & 1);
      c = ((q2 < 2) ? 512 : 1024) + h * 64 + d;
    }
    wT[idx] = (bf16)w[k * 1536 + c];
  }
}

template <int MH, int NH>
__device__ __forceinline__ void mm(f32x4 (&acc)[8][4],
                                   const bf16x8 (&a)[4][2],
                                   const bf16x8 (&b)[2][2]) {
#pragma unroll
  for (int fm = 0; fm < 4; ++fm)
#pragma unroll
    for (int fn = 0; fn < 2; ++fn)
#pragma unroll
      for (int ks = 0; ks < 2; ++ks)
        acc[MH * 4 + fm][NH * 2 + fn] =
            mfma_bf16_16x16x32(a[fm][ks], b[fn][ks], acc[MH * 4 + fm][NH * 2 + fn]);
}

// ---------------- QKV GEMM (R8 structure) + fused in-LDS dots epilogue ----------
// tn 0,1: q tiles -> LN + store qh [bh][n][d].
// tn 2..5: kv tile head-pair hp=tn-2 -> k-LN / v to LDS [d][n] swizzled, then
//          8 waves compute dots partials -> dTp (bf16) [bh][tm&15][4096].
__global__ __launch_bounds__(512, 2) void k_qkv_gemm(
    const bf16* __restrict__ A, const bf16* __restrict__ Bt,
    const float* __restrict__ qg, const float* __restrict__ qbeta,
    const float* __restrict__ kg, const float* __restrict__ kbeta,
    bf16* __restrict__ qh, bf16* __restrict__ dTp)
{
  extern __shared__ bf16 lds[];
  const int tid = threadIdx.x;
  const int lane = tid & 63;
  const int w = tid >> 6;        // 0..7
  const int wm = w >> 2;         // 0..1
  const int wn = w & 3;          // 0..3

  const int wg = blockIdx.x;
  const int swz = (wg & 7) * 96 + (wg >> 3);
  const int tn = swz % 6;
  const int tm = swz / 6;

  auto stA = [&](int buf, int slot, int ktile) {
#pragma unroll
    for (int i = 0; i < 2; ++i) {
      int vr = i * 64 + w * 8 + (lane >> 3);
      int grow = tm * 256 + (vr >> 6) * 128 + slot * 64 + (vr & 63);
      int gk = ktile * 64 + (((lane & 7) ^ (vr & 7)) * 8);
      gld_lds16(A + (size_t)grow * 512 + gk,
                (char*)lds + (buf * 2 + slot) * 16384 + i * 8192 + w * 1024);
    }
  };
  auto stB = [&](int buf, int slot, int ktile) {
#pragma unroll
    for (int i = 0; i < 2; ++i) {
      int vr = i * 64 + w * 8 + (lane >> 3);
      int grow = tn * 256 + (vr >> 5) * 64 + slot * 32 + (vr & 31);
      int gk = ktile * 64 + (((lane & 7) ^ (vr & 7)) * 8);
      gld_lds16(Bt + (size_t)grow * 512 + gk,
                (char*)lds + 65536 + (buf * 2 + slot) * 16384 + i * 8192 + w * 1024);
    }
  };
  auto rdA = [&](int buf, int mh, bf16x8 (&fr)[4][2]) {
    const bf16* base = lds + (buf * 2 + mh) * 8192;
#pragma unroll
    for (int f = 0; f < 4; ++f) {
      int vr = wm * 64 + f * 16 + (lane & 15);
#pragma unroll
      for (int ks = 0; ks < 2; ++ks) {
        int pb = (ks * 4 + (lane >> 4)) ^ (vr & 7);
        fr[f][ks] = *(const bf16x8*)(base + vr * 64 + pb * 8);
      }
    }
  };
  auto rdB = [&](int buf, int nh, bf16x8 (&fr)[2][2]) {
    const bf16* base = lds + 32768 + (buf * 2 + nh) * 8192;
#pragma unroll
    for (int f = 0; f < 2; ++f) {
      int vr = wn * 32 + f * 16 + (lane & 15);
#pragma unroll
      for (int ks = 0; ks < 2; ++ks) {
        int pb = (ks * 4 + (lane >> 4)) ^ (vr & 7);
        fr[f][ks] = *(const bf16x8*)(base + vr * 64 + pb * 8);
      }
    }
  };

  bf16x8 afr[4][2];
  bf16x8 bfr[2][2][2];
  f32x4 acc[8][4];
  {
    f32x4 z = {0.f, 0.f, 0.f, 0.f};
#pragma unroll
    for (int m = 0; m < 8; ++m)
#pragma unroll
      for (int n = 0; n < 4; ++n) acc[m][n] = z;
  }

  // ---- prologue: fully stage tiles 0 and 1 ----
  stA(0, 0, 0); stB(0, 0, 0); stA(0, 1, 0); stB(0, 1, 0);
  stA(1, 0, 1); stB(1, 0, 1); stA(1, 1, 1); stB(1, 1, 1);
  asm volatile("s_waitcnt vmcnt(8)" ::: "memory");
  BAR;

  for (int t = 0; t < 8; ++t) {
    const int d = t & 1;
    rdA(d, 0, afr);
    rdB(d, 0, bfr[0]);
    if (t >= 1 && t <= 6) stA(d ^ 1, 1, t + 1);
    BAR;
    LGKM0;
    PRIO1; mm<0, 0>(acc, afr, bfr[0]); PRIO0;
    BAR;

    rdB(d, 1, bfr[1]);
    if (t >= 1 && t <= 6) stB(d ^ 1, 1, t + 1);
    BAR;
    LGKM0;
    PRIO1; mm<0, 1>(acc, afr, bfr[1]); PRIO0;
    BAR;

    rdA(d, 1, afr);
    if (t <= 5) stA(d, 0, t + 2);
    BAR;
    LGKM0;
    PRIO1; mm<1, 0>(acc, afr, bfr[0]); PRIO0;
    BAR;

    if (t <= 5) stB(d, 0, t + 2);
    BAR;
    PRIO1; mm<1, 1>(acc, afr, bfr[1]); PRIO0;
    if (t < 6) { VMC(4); } else if (t == 6) { VMC(0); }
    BAR;
  }

  const int dlane = lane & 15;
  const int rsub = (lane >> 4) * 4;

  if (tn < 2) {
    // ---- q epilogue: LN + store [bh][n][d] ----
    const int hcol = tn * 4 + wn;
    float g4[4], b4[4];
#pragma unroll
    for (int fn = 0; fn < 4; ++fn) {
      g4[fn] = qg[fn * 16 + dlane];
      b4[fn] = qbeta[fn * 16 + dlane];
    }
#pragma unroll
    for (int m = 0; m < 8; ++m) {
      float mu[4], rs[4];
#pragma unroll
      for (int r = 0; r < 4; ++r) {
        float s  = acc[m][0][r] + acc[m][1][r] + acc[m][2][r] + acc[m][3][r];
        float s2 = acc[m][0][r] * acc[m][0][r] + acc[m][1][r] * acc[m][1][r]
                 + acc[m][2][r] * acc[m][2][r] + acc[m][3][r] * acc[m][3][r];
#pragma unroll
        for (int msk = 1; msk < 16; msk <<= 1) {
          s  += __shfl_xor(s, msk, 64);
          s2 += __shfl_xor(s2, msk, 64);
        }
        float mean = s * (1.0f / 64.0f);
        float var  = s2 * (1.0f / 64.0f) - mean * mean;
        mu[r] = mean;
        rs[r] = rsqrtf(var + 1e-5f);
      }
      int rowg = tm * 256 + wm * 128 + m * 16 + rsub;
      int bb2 = rowg >> 12, n0 = rowg & 4095;
      int bh = bb2 * 8 + hcol;
      bf16* dst = qh + ((size_t)bh * 4096 + n0) * 64;
#pragma unroll
      for (int r = 0; r < 4; ++r)
#pragma unroll
        for (int fn = 0; fn < 4; ++fn) {
          float xv = (acc[m][fn][r] - mu[r]) * rs[r] * g4[fn] + b4[fn];
          dst[(size_t)r * 64 + fn * 16 + dlane] = (bf16)xv;
        }
    }
  } else {
    // ---- kv epilogue: k-LN / v -> LDS [d][n] swizzled; then in-LDS dots ----
    const int hp = tn - 2;
    const bool isK = (wn < 2);
    const int hloc = wn & 1;
    char* reg = (char*)lds + ((isK ? 0 : 2) + hloc) * 32768;
    float g4[4], b4[4];
    if (isK) {
#pragma unroll
      for (int fn = 0; fn < 4; ++fn) {
        g4[fn] = kg[fn * 16 + dlane];
        b4[fn] = kbeta[fn * 16 + dlane];
      }
    }
#pragma unroll
    for (int m = 0; m < 8; ++m) {
      float mu[4] = {}, rs[4] = {};
      if (isK) {
#pragma unroll
        for (int r = 0; r < 4; ++r) {
          float s  = acc[m][0][r] + acc[m][1][r] + acc[m][2][r] + acc[m][3][r];
          float s2 = acc[m][0][r] * acc[m][0][r] + acc[m][1][r] * acc[m][1][r]
                   + acc[m][2][r] * acc[m][2][r] + acc[m][3][r] * acc[m][3][r];
#pragma unroll
          for (int msk = 1; msk < 16; msk <<= 1) {
            s  += __shfl_xor(s, msk, 64);
            s2 += __shfl_xor(s2, msk, 64);
          }
          float mean = s * (1.0f / 64.0f);
          float var  = s2 * (1.0f / 64.0f) - mean * mean;
          mu[r] = mean;
          rs[r] = rsqrtf(var + 1e-5f);
        }
      }
      int n0 = wm * 128 + m * 16 + rsub;
#pragma unroll
      for (int fn = 0; fn < 4; ++fn) {
        int dd = fn * 16 + dlane;
        bf16x4 pk;
#pragma unroll
        for (int r = 0; r < 4; ++r) {
          float xv = isK ? ((acc[m][fn][r] - mu[r]) * rs[r] * g4[fn] + b4[fn])
                         : acc[m][fn][r];
          pk[r] = (bf16)xv;
        }
        int blk = (n0 >> 2) ^ ((dd & 7) << 1);
        *(bf16x4*)(reg + dd * 512 + blk * 8) = pk;
      }
    }
    LGKM0;
    BAR;
    const int hsel = w >> 2;
    const int qd = w & 3;
    const char* Abase = (char*)lds + (2 + hsel) * 32768;  // vT (e rows)
    const char* Bbase = (char*)lds + hsel * 32768;        // kT (dk rows)
    f32x4 dacc[4] = {};
#pragma unroll
    for (int t8 = 0; t8 < 8; ++t8) {
      int blkb = t8 * 8 + (lane >> 4) * 2;
      int rA = qd * 16 + dlane;
      bf16x8 va = *(const bf16x8*)(Abase + rA * 512 + (blkb ^ ((rA & 7) << 1)) * 8);
#pragma unroll
      for (int j = 0; j < 4; ++j) {
        int rB = j * 16 + dlane;
        bf16x8 vb = *(const bf16x8*)(Bbase + rB * 512 + (blkb ^ ((rB & 7) << 1)) * 8);
        dacc[j] = mfma_bf16_16x16x32(va, vb, dacc[j]);
      }
    }
    int bh = (tm >> 4) * 8 + 2 * hp + hsel;
    bf16* outp = dTp + ((size_t)bh * 16 + (tm & 15)) * 4096;
#pragma unroll
    for (int j = 0; j < 4; ++j)
#pragma unroll
      for (int r = 0; r < 4; ++r) {
        int e = qd * 16 + (lane >> 4) * 4 + r;
        outp[e * 64 + j * 16 + dlane] = (bf16)dacc[j][r];
      }
  }
}

// ---------------- reduce 16 bf16 dots partials, cast to bf16 ----------------
__global__ __launch_bounds__(256) void k_cvt_dt(const bf16* __restrict__ dTp,
                                                bf16* __restrict__ dTb) {
  int j = blockIdx.x * 256 + threadIdx.x;   // 262144 = 64 bh * 4096
  int bh = j >> 12;
  int i = j & 4095;
  const bf16* p = dTp + (size_t)bh * 65536 + i;
  float s = 0.f;
#pragma unroll
  for (int c = 0; c < 16; ++c) s += (float)p[c * 4096];
  dTb[j] = (bf16)s;
}

// ---------------- out = (Q @ dots) / n ----------------
__global__ __launch_bounds__(256) void k_out(const bf16* __restrict__ qh,
                                             const bf16* __restrict__ dTb,
                                             float* __restrict__ out) {
  __shared__ bf16 lA[128 * 64];
  const int tid = threadIdx.x, lane = tid & 63, w = tid >> 6;
  const int wm = w >> 1, wn = w & 1;
  const int bh = blockIdx.y, mt = blockIdx.x;
  const int bb = bh >> 3, h = bh & 7;
  const bf16* Ab = qh + (size_t)bh * 4096 * 64 + (size_t)mt * 128 * 64;
  const int srow = lane >> 3, sblk = (lane & 7) ^ srow;
#pragma unroll
  for (int i = 0; i < 4; ++i) {
    int slot = w * 4 + i;
    int row = slot * 8 + srow;
    gld_lds16(Ab + (size_t)row * 64 + sblk * 8, (char*)lA + slot * 1024);
  }
  __syncthreads();
  const bf16* Bb = dTb + (size_t)bh * 4096;
  f32x4 acc[4][2] = {};
#pragma unroll
  for (int ks = 0; ks < 2; ++ks) {
    bf16x8 af[4], bq[2];
#pragma unroll
    for (int f = 0; f < 4; ++f) {
      int row = wm * 64 + f * 16 + (lane & 15);
      int sb = (ks * 4 + (lane >> 4)) ^ (row & 7);
      af[f] = *(const bf16x8*)(lA + row * 64 + sb * 8);
    }
#pragma unroll
    for (int fn = 0; fn < 2; ++fn) {
      int e = wn * 32 + fn * 16 + (lane & 15);
      bq[fn] = *(const bf16x8*)(Bb + e * 64 + ks * 32 + (lane >> 4) * 8);
    }
#pragma unroll
    for (int fm = 0; fm < 4; ++fm)
#pragma unroll
      for (int fn = 0; fn < 2; ++fn)
        acc[fm][fn] = mfma_bf16_16x16x32(af[fm], bq[fn], acc[fm][fn]);
  }
#pragma unroll
  for (int fm = 0; fm < 4; ++fm)
#pragma unroll
    for (int fn = 0; fn < 2; ++fn)
#pragma unroll
      for (int r = 0; r < 4; ++r) {
        int n = mt * 128 + wm * 64 + fm * 16 + (lane >> 4) * 4 + r;
        int e = wn * 32 + fn * 16 + (lane & 15);
        out[((size_t)bb * 4096 + n) * 512 + h * 64 + e] = acc[fm][fn][r] * (1.0f / 4096.0f);
      }
}

extern "C" void kernel_launch(void* const* d_in, const int* in_sizes, int n_in,
                              void* d_out, int out_size, void* d_ws, size_t ws_size,
                              hipStream_t stream) {
  const float* x  = (const float*)d_in[0];
  const float* wq = (const float*)d_in[1];
  const float* qg = (const float*)d_in[2];
  const float* qb = (const float*)d_in[3];
  const float* kg = (const float*)d_in[4];
  const float* kb = (const float*)d_in[5];
  float* out = (float*)d_out;
  char* ws = (char*)d_ws;

  bf16* xb  = (bf16*)(ws);                          // 32 MB  [32768][512]
  bf16* wT  = (bf16*)(ws + ((size_t)32 << 20));     // 1.5 MB [1536][512] permuted
  bf16* qh  = (bf16*)(ws + ((size_t)34 << 20));     // 32 MB  [64][4096][64]
  bf16* dTp = (bf16*)(ws + ((size_t)66 << 20));     // 8.4 MB [64][16][4096] bf16
  bf16* dTb = (bf16*)(ws + ((size_t)75 << 20));     // 0.5 MB

  k_prep<<<11264, 256, 0, stream>>>(x, xb, wq, wT);
  k_qkv_gemm<<<768, 512, 131072, stream>>>(xb, wT, qg, qb, kg, kb, qh, dTp);
  k_cvt_dt<<<1024, 256, 0, stream>>>(dTp, dTb);
  k_out<<<dim3(32, 64), 256, 0, stream>>>(qh, dTb, out);
}